// Round 14
// baseline (812.528 us; speedup 1.0000x reference)
//
#include <hip/hip_runtime.h>
#include <cstdio>

#define BB 4
#define C 64
#define HH 192
#define WW 192
#define NPIX (HH*WW)            /* 36864 */
#define ST (BB*C*NPIX)          /* 9437184 floats per tensor */

__device__ __forceinline__ float gelu_f(float v) {
    return 0.5f * v * (1.0f + erff(v * 0.70710678118654752440f));
}

// ---- fp16 pair helpers (dot2 path). h2 uses __fp16 to match the native
// return type of __builtin_amdgcn_cvt_pkrtz on gfx950 (R10 compile fix). ----
typedef __fp16 h2 __attribute__((ext_vector_type(2)));

__device__ __forceinline__ h2 pkh2(float lo, float hi) {
#if __has_builtin(__builtin_amdgcn_cvt_pkrtz)
    return __builtin_amdgcn_cvt_pkrtz(lo, hi);
#else
    h2 r; r[0] = (__fp16)lo; r[1] = (__fp16)hi; return r;
#endif
}

__device__ __forceinline__ float dot2f(h2 a, h2 b, float c) {
#if __has_builtin(__builtin_amdgcn_fdot2)
    return __builtin_amdgcn_fdot2(a, b, c, false);
#else
    return c + (float)a[0]*(float)b[0] + (float)a[1]*(float)b[1];
#endif
}

__device__ __forceinline__ void ld4h2(const void* p, h2* d) {
    const float4 f = *reinterpret_cast<const float4*>(p);
    d[0] = __builtin_bit_cast(h2, f.x);
    d[1] = __builtin_bit_cast(h2, f.y);
    d[2] = __builtin_bit_cast(h2, f.z);
    d[3] = __builtin_bit_cast(h2, f.w);
}

// ---- shared transpose-tile body (32x32 tile via LDS, tile[32][33]) ----
__device__ __forceinline__ void tr_tile(const float* __restrict__ img,
                                        float* __restrict__ og,
                                        int x0, int y0, int t, float* tile)
{
    const int tx = t & 31, ty = t >> 5;
#pragma unroll
    for (int r = ty; r < 32; r += 8) tile[r*33 + tx] = img[(y0+r)*WW + x0+tx];
    __syncthreads();
#pragma unroll
    for (int r = ty; r < 32; r += 8) og[(x0+r)*WW + (y0+tx)] = tile[tx*33 + r];
}

// ---------------------------------------------------------------------------
// GEMM-style 1x1 conv (R8-validated). 64(o) x 128(px) tile, 256 thr,
// acc[8][4]/thread. LDS 51200 B -> 3 blocks/CU.
// ---------------------------------------------------------------------------
template<bool TWO_IN, bool PERB, bool DO_GELU>
__global__ __launch_bounds__(256, 3) void k_gconv(
    const float* __restrict__ in1, const float* __restrict__ in2,
    const float* __restrict__ W1, const float* __restrict__ W2,
    const float* __restrict__ bias1, const float* __restrict__ bias2,
    float* __restrict__ out, int ldw1, int ldw2)
{
    extern __shared__ float sm[];
    float* Wl = sm;            // [64][68]  Wl[c][o] = W[o][c]
    float* Xl = sm + 4352;     // [64][132] Xl[c][p]
    const int t = threadIdx.x;
    const int px0 = blockIdx.x * 128;
    const int b = blockIdx.y;
    const size_t base = (size_t)b*(C*NPIX) + px0;
    const int to = t >> 5, tp = t & 31;
    const int o0 = to*8, p0 = tp*4;
    float acc[8][4];
#pragma unroll
    for (int k = 0; k < 8; ++k) {
        float bo = 0.f;
        if (bias1) bo += bias1[o0+k];
        if (bias2) bo += bias2[o0+k];
#pragma unroll
        for (int m = 0; m < 4; ++m) acc[k][m] = bo;
    }
    const int NIN = TWO_IN ? 2 : 1;
#pragma unroll
    for (int inp = 0; inp < NIN; ++inp) {
        const float* In = inp ? in2 : in1;
        const float* Wk = inp ? W2 : (PERB ? W1 + b*4096 : W1);
        const int ldw = inp ? ldw2 : ldw1;
#pragma unroll
        for (int k = 0; k < 16; ++k) {
            const int idx = k*256 + t;
            const int o = idx >> 6, c = idx & 63;
            Wl[c*68 + o] = Wk[o*ldw + c];
        }
#pragma unroll
        for (int k = 0; k < 8; ++k) {
            const int f4 = k*256 + t;
            const int c = f4 >> 5, p4 = (f4 & 31)*4;
            *reinterpret_cast<float4*>(&Xl[c*132 + p4]) =
                *reinterpret_cast<const float4*>(&In[base + (size_t)c*NPIX + p4]);
        }
        __syncthreads();
#pragma unroll 2
        for (int c = 0; c < 64; ++c) {
            const float4 wa = *reinterpret_cast<const float4*>(&Wl[c*68 + o0]);
            const float4 wb = *reinterpret_cast<const float4*>(&Wl[c*68 + o0 + 4]);
            const float4 xv = *reinterpret_cast<const float4*>(&Xl[c*132 + p0]);
            const float wr[8] = {wa.x,wa.y,wa.z,wa.w, wb.x,wb.y,wb.z,wb.w};
            const float xr[4] = {xv.x,xv.y,xv.z,xv.w};
#pragma unroll
            for (int k = 0; k < 8; ++k)
#pragma unroll
                for (int m = 0; m < 4; ++m) acc[k][m] += wr[k]*xr[m];
        }
        __syncthreads();
    }
#pragma unroll
    for (int k = 0; k < 8; ++k) {
        float4 o4;
        if (DO_GELU) {
            o4.x = gelu_f(acc[k][0]); o4.y = gelu_f(acc[k][1]);
            o4.z = gelu_f(acc[k][2]); o4.w = gelu_f(acc[k][3]);
        } else {
            o4.x = acc[k][0]; o4.y = acc[k][1];
            o4.z = acc[k][2]; o4.w = acc[k][3];
        }
        *reinterpret_cast<float4*>(&out[base + (size_t)(o0+k)*NPIX + p0]) = o4;
    }
}

// ---------------------------------------------------------------------------
// FUSED final conv: out = gelu(W1@i1 + W2@i2 + W3@i3 + W4@i4 + bias).
// ---------------------------------------------------------------------------
__global__ __launch_bounds__(256, 3) void k_conv4(
    const float* __restrict__ i1, const float* __restrict__ i2,
    const float* __restrict__ i3, const float* __restrict__ i4,
    const float* __restrict__ W1, const float* __restrict__ W2,
    const float* __restrict__ W3, const float* __restrict__ W4,
    const float* __restrict__ bias, float* __restrict__ out)
{
    extern __shared__ float sm[];
    float* Wl = sm;            // [64][68]
    float* Xl = sm + 4352;     // [64][132]
    const int t = threadIdx.x;
    const int px0 = blockIdx.x * 128;
    const int b = blockIdx.y;
    const size_t base = (size_t)b*(C*NPIX) + px0;
    const int to = t >> 5, tp = t & 31;
    const int o0 = to*8, p0 = tp*4;
    float acc[8][4];
#pragma unroll
    for (int k = 0; k < 8; ++k) {
        const float bo = bias[o0+k];
#pragma unroll
        for (int m = 0; m < 4; ++m) acc[k][m] = bo;
    }
#pragma unroll
    for (int inp = 0; inp < 4; ++inp) {
        const float* In = (inp==0)?i1:(inp==1)?i2:(inp==2)?i3:i4;
        const float* Wk = (inp==0)?W1:(inp==1)?W2:(inp==2)?W3:W4;
        const int ldw = (inp==0)?192:64;
#pragma unroll
        for (int k = 0; k < 16; ++k) {
            const int idx = k*256 + t;
            const int o = idx >> 6, c = idx & 63;
            Wl[c*68 + o] = Wk[o*ldw + c];
        }
#pragma unroll
        for (int k = 0; k < 8; ++k) {
            const int f4 = k*256 + t;
            const int c = f4 >> 5, p4 = (f4 & 31)*4;
            *reinterpret_cast<float4*>(&Xl[c*132 + p4]) =
                *reinterpret_cast<const float4*>(&In[base + (size_t)c*NPIX + p4]);
        }
        __syncthreads();
#pragma unroll 2
        for (int c = 0; c < 64; ++c) {
            const float4 wa = *reinterpret_cast<const float4*>(&Wl[c*68 + o0]);
            const float4 wb = *reinterpret_cast<const float4*>(&Wl[c*68 + o0 + 4]);
            const float4 xv = *reinterpret_cast<const float4*>(&Xl[c*132 + p0]);
            const float wr[8] = {wa.x,wa.y,wa.z,wa.w, wb.x,wb.y,wb.z,wb.w};
            const float xr[4] = {xv.x,xv.y,xv.z,xv.w};
#pragma unroll
            for (int k = 0; k < 8; ++k)
#pragma unroll
                for (int m = 0; m < 4; ++m) acc[k][m] += wr[k]*xr[m];
        }
        __syncthreads();
    }
#pragma unroll
    for (int k = 0; k < 8; ++k) {
        float4 o4;
        o4.x = gelu_f(acc[k][0]); o4.y = gelu_f(acc[k][1]);
        o4.z = gelu_f(acc[k][2]); o4.w = gelu_f(acc[k][3]);
        *reinterpret_cast<float4*>(&out[base + (size_t)(o0+k)*NPIX + p0]) = o4;
    }
}

// ---------------------------------------------------------------------------
// Depthwise 3x3 (pad 1) + bias + GELU.  grid = (H, B*C), block = 192 (=W).
// ---------------------------------------------------------------------------
__global__ __launch_bounds__(192) void k_dw(
    const float* __restrict__ t0, const float* __restrict__ w,
    const float* __restrict__ bias, float* __restrict__ g)
{
    const int x = threadIdx.x;
    const int y = blockIdx.x;
    const int bc = blockIdx.y;
    const int c = bc & 63;
    const float* img = t0 + bc * NPIX;
    const float* wc = w + c * 9;
    float acc = bias[c];
#pragma unroll
    for (int dy = -1; dy <= 1; ++dy) {
        const int yy = y + dy;
        if (yy < 0 || yy > 191) continue;
#pragma unroll
        for (int dx = -1; dx <= 1; ++dx) {
            const int xx = x + dx;
            if (xx < 0 || xx > 191) continue;
            acc += img[yy*WW + xx] * wc[(dy+1)*3 + (dx+1)];
        }
    }
    g[bc*NPIX + y*WW + x] = gelu_f(acc);
}

// ---------------------------------------------------------------------------
// MERGED: gram_part blocks (bid<576, dispatched first) + A->Cf transpose
// tiles (9216 blocks backfill the gram tail). Disjoint outputs; both need
// only A. LDS = gram's 69632 B (transpose uses first 4224 B).
// ---------------------------------------------------------------------------
__global__ __launch_bounds__(256) void k_gram_tr(
    const float* __restrict__ x1p, float* __restrict__ part,
    float* __restrict__ tout)
{
    extern __shared__ float lt[];     // gram: [256][68]; transpose: [32][33]
    const int bid = blockIdx.x, t = threadIdx.x;
    if (bid < 576) {
        const int chunk = bid % 144, b = bid / 144;
        const int gbase = b * (C*NPIX) + chunk * 256;
        for (int idx = t; idx < C*256; idx += 256) {
            const int c = idx >> 8, n = idx & 255;
            lt[n*68 + c] = x1p[gbase + c*NPIX + n];
        }
        __syncthreads();
        const int ti = t & 15, tj = t >> 4;
        float acc[4][4];
#pragma unroll
        for (int r = 0; r < 4; ++r)
#pragma unroll
            for (int s = 0; s < 4; ++s) acc[r][s] = 0.f;
        for (int n = 0; n < 256; ++n) {
            const float4 av = *reinterpret_cast<const float4*>(&lt[n*68 + 4*ti]);
            const float4 bv = *reinterpret_cast<const float4*>(&lt[n*68 + 4*tj]);
            const float ar[4] = {av.x, av.y, av.z, av.w};
            const float br[4] = {bv.x, bv.y, bv.z, bv.w};
#pragma unroll
            for (int r = 0; r < 4; ++r)
#pragma unroll
                for (int s = 0; s < 4; ++s) acc[r][s] += ar[r] * br[s];
        }
        float* pb = part + (b*144 + chunk)*4096;
#pragma unroll
        for (int r = 0; r < 4; ++r)
#pragma unroll
            for (int s = 0; s < 4; ++s) pb[(4*ti+r)*64 + (4*tj+s)] = acc[r][s];
    } else {
        const int tb = bid - 576;              // 0..9215
        const int z = tb / 36, rem = tb % 36;
        const int x0 = (rem % 6) * 32, y0 = (rem / 6) * 32;
        tr_tile(x1p + (size_t)z*NPIX, tout + (size_t)z*NPIX, x0, y0, t, lt);
    }
}

__global__ __launch_bounds__(256) void k_gram_reduce(
    const float* __restrict__ part, float* __restrict__ G1)
{
    const int flat = blockIdx.x*256 + threadIdx.x;   // < 16384
    const int b = flat >> 12, ij = flat & 4095;
    float s = 0.f;
    for (int ch = 0; ch < 144; ++ch) s += part[(b*144+ch)*4096 + ij];
    G1[flat] = s;
}

// ---------------------------------------------------------------------------
// Channel-attention collapse: per batch, M2 = Wp * blockdiag(attn) * Wv.
// ---------------------------------------------------------------------------
__global__ __launch_bounds__(256) void k_attn_small(
    const float* __restrict__ G1a, const float* __restrict__ Wq,
    const float* __restrict__ Wk, const float* __restrict__ Wv,
    const float* __restrict__ Wp, const float* __restrict__ temp,
    float* __restrict__ M2)
{
    extern __shared__ float sm[];
    float* g1 = sm;
    float* wa = sm + 4096;
    float* wb = sm + 8192;
    float* u  = sm + 12288;
    float* at = sm + 16384;
    float* nq = sm + 18432;
    float* nk = sm + 18496;
    const int b = blockIdx.x, t = threadIdx.x;
    const float* G = G1a + b*4096;
    for (int i = t; i < 4096; i += 256) { g1[i] = G[i]; wa[i] = Wq[i]; wb[i] = Wk[i]; }
    __syncthreads();
    {
        const int r = t >> 2, q4 = t & 3;
        for (int cc = q4*16; cc < q4*16 + 16; ++cc) {
            float s = 0.f;
            for (int k = 0; k < 64; ++k) s += wa[r*64+k] * g1[k*64+cc];
            u[r*64+cc] = s;
        }
    }
    __syncthreads();
    {
        const int d = t >> 2, kq = t & 3;
        float p = 0.f;
        for (int k = kq*16; k < kq*16 + 16; ++k) {
            float tk = 0.f;
            for (int c2 = 0; c2 < 64; ++c2) tk += g1[k*64+c2] * wb[d*64+c2];
            p += wb[d*64+k] * tk;
        }
        p += __shfl_xor(p, 1);
        p += __shfl_xor(p, 2);
        if (kq == 0) nk[d] = sqrtf(fmaxf(p, 0.f));
    }
    if (t < 64) {
        float s = 0.f;
        for (int c2 = 0; c2 < 64; ++c2) s += u[t*64+c2] * wa[t*64+c2];
        nq[t] = sqrtf(fmaxf(s, 0.f));
    }
    __syncthreads();
    if (t < 64) {
        const int gI = t >> 5;
        const float tg = temp[gI];
        const float dq = fmaxf(nq[t], 1e-12f);
        float row[32];
        float mx = -1e30f;
#pragma unroll
        for (int d2 = 0; d2 < 32; ++d2) {
            const int dd = gI*32 + d2;
            float s = 0.f;
            for (int c2 = 0; c2 < 64; ++c2) s += u[t*64+c2] * wb[dd*64+c2];
            s = s * tg / (dq * fmaxf(nk[dd], 1e-12f));
            row[d2] = s; mx = fmaxf(mx, s);
        }
        float se = 0.f;
#pragma unroll
        for (int d2 = 0; d2 < 32; ++d2) { row[d2] = __expf(row[d2]-mx); se += row[d2]; }
        const float inv = 1.f / se;
#pragma unroll
        for (int d2 = 0; d2 < 32; ++d2) at[t*32+d2] = row[d2]*inv;
    }
    __syncthreads();
    for (int i = t; i < 4096; i += 256) { wa[i] = Wv[i]; wb[i] = Wp[i]; }
    __syncthreads();
    {
        const int m = t >> 2, q4 = t & 3, gI = m >> 5;
        for (int e = q4*16; e < q4*16 + 16; ++e) {
            float s = 0.f;
#pragma unroll
            for (int d2 = 0; d2 < 32; ++d2) s += at[m*32+d2] * wa[(gI*32+d2)*64 + e];
            g1[m*64+e] = s;
        }
    }
    __syncthreads();
    {
        const int o = t >> 2, q4 = t & 3;
        for (int e = q4*16; e < q4*16 + 16; ++e) {
            float s = 0.f;
            for (int m = 0; m < 64; ++m) s += wb[o*64+m] * g1[m*64+e];
            M2[b*4096 + o*64+e] = s;
        }
    }
}

// ---------------------------------------------------------------------------
// Small weight-folding products (unchanged).
// ---------------------------------------------------------------------------
__global__ __launch_bounds__(256) void k_small_mats(
    const float* __restrict__ rq, const float* __restrict__ rk,
    const float* __restrict__ cq, const float* __restrict__ ck,
    const float* __restrict__ fw, const float* __restrict__ rv,
    const float* __restrict__ cv, const float* __restrict__ rg,
    const float* __restrict__ cg,
    float* __restrict__ Wtr, float* __restrict__ Wtc,
    float* __restrict__ Wf2p, float* __restrict__ Wf3p,
    float* __restrict__ Wfx)
{
    const int which = blockIdx.x, t = threadIdx.x;
    const int a = t >> 2, b0 = (t & 3) * 16;
    if (which <= 1) {
        const float* Q = which ? cq : rq;
        const float* Kw = which ? ck : rk;
        float* O = which ? Wtc : Wtr;
        for (int b = b0; b < b0 + 16; ++b) {
            float s = 0.f;
            for (int co = 0; co < 64; ++co) s += Q[co*64 + a] * Kw[co*64 + b];
            O[a*64 + b] = s;
        }
    } else if (which <= 3) {
        const float* Vw = (which == 2) ? rv : cv;
        const float g = (which == 2) ? rg[0] : cg[0];
        const int off = (which == 2) ? 64 : 128;
        float* O = (which == 2) ? Wf2p : Wf3p;
        for (int b = b0; b < b0 + 16; ++b) {
            float s = 0.f;
            for (int m = 0; m < 64; ++m) s += fw[a*192 + off + m] * Vw[m*64 + b];
            O[a*64 + b] = g * s;
        }
    } else {
        for (int b = b0; b < b0 + 16; ++b)
            Wfx[a*64 + b] = fw[a*192 + 64 + b] + fw[a*192 + 128 + b];
    }
}

// ---------------------------------------------------------------------------
// Per-line attention body (R13: 132us/dispatch). dot2 math, 2 blocks/CU.
// ---------------------------------------------------------------------------
#define SP 196
#define PSTR 100
__device__ __forceinline__ void attn_body(
    const float* __restrict__ X, const float* __restrict__ Wt,
    const float* __restrict__ U, float* __restrict__ Z,
    int h, int b, int t, float* sm)
{
    h2* Xh = reinterpret_cast<h2*>(sm);            // [32][196] pairs along c
    h2* Yh = reinterpret_cast<h2*>(sm + 6272);     // [32][196] pairs along c
    h2* Ph = reinterpret_cast<h2*>(sm);            // [192][100] pairs along j
    float* red  = sm;                              // [192][17] overlay (ph3)
    float* mrow = sm + 3264;                       // 192 (in dead Xh)
    float* lrow = sm + 19200;                      // 192, persistent @76800B
    const size_t gbase = (size_t)b*(C*NPIX) + (size_t)h*WW;

    // --- phase 0: load X line (vectorized), pack fp16 pairs along c ---
#pragma unroll
    for (int k = 0; k < 6; ++k) {
        const int idx = k*256 + t;                 // < 32*48
        const int cc = idx / 48, jg = (idx - cc*48) * 4;
        const float4 lo = *reinterpret_cast<const float4*>(
            &X[gbase + (size_t)(2*cc)*NPIX + jg]);
        const float4 hi = *reinterpret_cast<const float4*>(
            &X[gbase + (size_t)(2*cc+1)*NPIX + jg]);
        float4 o;
        o.x = __builtin_bit_cast(float, pkh2(lo.x, hi.x));
        o.y = __builtin_bit_cast(float, pkh2(lo.y, hi.y));
        o.z = __builtin_bit_cast(float, pkh2(lo.z, hi.z));
        o.w = __builtin_bit_cast(float, pkh2(lo.w, hi.w));
        *reinterpret_cast<float4*>(&Xh[cc*SP + jg]) = o;
    }
    __syncthreads();

    // --- phase 1: Y = sum_a Wt[a][c] X[a][j], dot2 pairs along a ---
    {
        const int tc = t & 15, tjy = t >> 4;
        const int c0 = 4*tc, j0y = 12*tjy;
        float accy[4][12];
#pragma unroll
        for (int k = 0; k < 4; ++k)
#pragma unroll
            for (int m = 0; m < 12; ++m) accy[k][m] = 0.f;
        for (int aa = 0; aa < 32; ++aa) {
            const float4 wlo = *reinterpret_cast<const float4*>(&Wt[(2*aa)*64 + c0]);
            const float4 whi = *reinterpret_cast<const float4*>(&Wt[(2*aa+1)*64 + c0]);
            h2 wh[4];
            wh[0] = pkh2(wlo.x, whi.x); wh[1] = pkh2(wlo.y, whi.y);
            wh[2] = pkh2(wlo.z, whi.z); wh[3] = pkh2(wlo.w, whi.w);
            h2 xh[12];
            ld4h2(&Xh[aa*SP + j0y],     xh);
            ld4h2(&Xh[aa*SP + j0y + 4], xh+4);
            ld4h2(&Xh[aa*SP + j0y + 8], xh+8);
#pragma unroll
            for (int k = 0; k < 4; ++k)
#pragma unroll
                for (int m = 0; m < 12; ++m)
                    accy[k][m] = dot2f(wh[k], xh[m], accy[k][m]);
        }
#pragma unroll
        for (int m = 0; m < 12; ++m) {
            Yh[(2*tc)*SP + j0y + m]   = pkh2(accy[0][m], accy[1][m]);
            Yh[(2*tc+1)*SP + j0y + m] = pkh2(accy[2][m], accy[3][m]);
        }
    }
    __syncthreads();

    // --- phase 2: S = X^T Y, dot2 pairs along c, fp32 12x12 acc ---
    const int ti = t & 15, tj = t >> 4;
    const int i0 = ti*12, j0 = tj*12;
    float acc[12][12];
#pragma unroll
    for (int r = 0; r < 12; ++r)
#pragma unroll
        for (int s = 0; s < 12; ++s) acc[r][s] = 0.f;
#pragma unroll 2
    for (int cc = 0; cc < 32; ++cc) {
        h2 xh[12], yh[12];
        ld4h2(&Xh[cc*SP + i0],     xh);
        ld4h2(&Xh[cc*SP + i0 + 4], xh+4);
        ld4h2(&Xh[cc*SP + i0 + 8], xh+8);
        ld4h2(&Yh[cc*SP + j0],     yh);
        ld4h2(&Yh[cc*SP + j0 + 4], yh+4);
        ld4h2(&Yh[cc*SP + j0 + 8], yh+8);
#pragma unroll
        for (int r = 0; r < 12; ++r)
#pragma unroll
            for (int s = 0; s < 12; ++s)
                acc[r][s] = dot2f(xh[r], yh[s], acc[r][s]);
    }
    __syncthreads();   // Xh/Yh dead; red overlays Xh

    // --- phase 3: softmax over rows (fp32; P~ left unnormalized) ---
#pragma unroll
    for (int r = 0; r < 12; ++r) {
        float pm = acc[r][0];
#pragma unroll
        for (int s = 1; s < 12; ++s) pm = fmaxf(pm, acc[r][s]);
        red[(i0 + r)*17 + tj] = pm;
    }
    __syncthreads();
    if (t < 192) {
        float m = red[t*17];
#pragma unroll
        for (int k = 1; k < 16; ++k) m = fmaxf(m, red[t*17 + k]);
        mrow[t] = m;
    }
    __syncthreads();
#pragma unroll
    for (int r = 0; r < 12; ++r) {
        const float mi = mrow[i0 + r];
        float ps = 0.f;
#pragma unroll
        for (int s = 0; s < 12; ++s) {
            acc[r][s] = __expf(acc[r][s] - mi);
            ps += acc[r][s];
        }
        red[(i0 + r)*17 + tj] = ps;
    }
    __syncthreads();
    if (t < 192) {
        float l = 0.f;
#pragma unroll
        for (int k = 0; k < 16; ++k) l += red[t*17 + k];
        lrow[t] = 1.f / l;
    }
    __syncthreads();

    // --- phase 4: store unnormalized P~ fp16, pairs along j ---
    {
        const int jh0 = j0 >> 1;       // 6*tj
#pragma unroll
        for (int r = 0; r < 12; ++r)
#pragma unroll
            for (int q = 0; q < 6; ++q)
                Ph[(i0 + r)*PSTR + jh0 + q] = pkh2(acc[r][2*q], acc[r][2*q+1]);
    }
    __syncthreads();

    // --- phase 5: Z = lrow * (U @ P~^T); U cvt'd on fly, dot2 along j ---
    const int ci = t & 15, ii = t >> 4;
    const int c0z = 4*ci, i0z = 12*ii;
    const float* Ub = U + gbase;
    float accz[4][12];
#pragma unroll
    for (int k = 0; k < 4; ++k)
#pragma unroll
        for (int m = 0; m < 12; ++m) accz[k][m] = 0.f;
    for (int jt = 0; jt < 192; jt += 8) {
        h2 uh[4][4];
#pragma unroll
        for (int k = 0; k < 4; ++k) {
            const float4 ua = *reinterpret_cast<const float4*>(&Ub[(size_t)(c0z+k)*NPIX + jt]);
            const float4 ub = *reinterpret_cast<const float4*>(&Ub[(size_t)(c0z+k)*NPIX + jt + 4]);
            uh[k][0] = pkh2(ua.x, ua.y); uh[k][1] = pkh2(ua.z, ua.w);
            uh[k][2] = pkh2(ub.x, ub.y); uh[k][3] = pkh2(ub.z, ub.w);
        }
        h2 ph[12][4];
#pragma unroll
        for (int m = 0; m < 12; ++m)
            ld4h2(&Ph[(i0z+m)*PSTR + (jt >> 1)], ph[m]);
#pragma unroll
        for (int k = 0; k < 4; ++k)
#pragma unroll
            for (int m = 0; m < 12; ++m) {
                float a = accz[k][m];
                a = dot2f(uh[k][0], ph[m][0], a);
                a = dot2f(uh[k][1], ph[m][1], a);
                a = dot2f(uh[k][2], ph[m][2], a);
                a = dot2f(uh[k][3], ph[m][3], a);
                accz[k][m] = a;
            }
    }
    float lr[12];
#pragma unroll
    for (int m = 0; m < 12; ++m) lr[m] = lrow[i0z + m];
#pragma unroll
    for (int k = 0; k < 4; ++k) {
        float* zr = Z + gbase + (size_t)(c0z + k)*NPIX + i0z;
        float4 o0, o1, o2;
        o0.x = accz[k][0]*lr[0]; o0.y = accz[k][1]*lr[1];  o0.z = accz[k][2]*lr[2];   o0.w = accz[k][3]*lr[3];
        o1.x = accz[k][4]*lr[4]; o1.y = accz[k][5]*lr[5];  o1.z = accz[k][6]*lr[6];   o1.w = accz[k][7]*lr[7];
        o2.x = accz[k][8]*lr[8]; o2.y = accz[k][9]*lr[9];  o2.z = accz[k][10]*lr[10]; o2.w = accz[k][11]*lr[11];
        *reinterpret_cast<float4*>(zr)     = o0;
        *reinterpret_cast<float4*>(zr + 4) = o1;
        *reinterpret_cast<float4*>(zr + 8) = o2;
    }
}

// Col attention: pure attn, grid (192, B).
__global__ __launch_bounds__(256, 2) void k_attn_fused(
    const float* __restrict__ X, const float* __restrict__ Wt,
    const float* __restrict__ U, float* __restrict__ Z)
{
    extern __shared__ float sm[];
    attn_body(X, Wt, U, Z, blockIdx.x, blockIdx.y, threadIdx.x, sm);
}

// MERGED: row attention (bid<768, first) + Ef->Df transpose tiles (9216
// blocks backfill the attn tail). Buffers disjoint: attn reads A/Bf writes
// Cf; transpose reads Ef writes Df (Ef complete after step 7; Df consumed
// only by conv4).
__global__ __launch_bounds__(256, 2) void k_attn_row_tr(
    const float* __restrict__ X, const float* __restrict__ Wt,
    const float* __restrict__ U, float* __restrict__ Z,
    const float* __restrict__ tin, float* __restrict__ tout)
{
    extern __shared__ float sm[];
    const int bid = blockIdx.x, t = threadIdx.x;
    if (bid < 768) {
        attn_body(X, Wt, U, Z, bid % 192, bid / 192, t, sm);
    } else {
        const int tb = bid - 768;              // 0..9215
        const int z = tb / 36, rem = tb % 36;
        const int x0 = (rem % 6) * 32, y0 = (rem / 6) * 32;
        tr_tile(tin + (size_t)z*NPIX, tout + (size_t)z*NPIX, x0, y0, t, sm);
    }
}

// ---------------------------------------------------------------------------
// HW transpose per image: out[img][x][y] = in[img][y][x]. grid (6,6,B*C).
// ---------------------------------------------------------------------------
__global__ __launch_bounds__(256) void k_transpose(
    const float* __restrict__ in, float* __restrict__ out)
{
    __shared__ float tile[32*33];
    tr_tile(in + (size_t)blockIdx.z*NPIX, out + (size_t)blockIdx.z*NPIX,
            blockIdx.x*32, blockIdx.y*32, threadIdx.x, tile);
}

// ---------------------------------------------------------------------------
extern "C" void kernel_launch(void* const* d_in, const int* in_sizes, int n_in,
                              void* d_out, int out_size, void* d_ws, size_t ws_size,
                              hipStream_t stream) {
    const float* x       = (const float*)d_in[0];
    const float* pw_w    = (const float*)d_in[1];
    const float* dw_w    = (const float*)d_in[2];
    const float* dw_b    = (const float*)d_in[3];
    const float* conv2_w = (const float*)d_in[4];
    const float* conv2_b = (const float*)d_in[5];
    const float* conv0_w = (const float*)d_in[6];
    const float* conv0_b = (const float*)d_in[7];
    const float* attq    = (const float*)d_in[8];
    const float* attk    = (const float*)d_in[9];
    const float* attv    = (const float*)d_in[10];
    const float* attp    = (const float*)d_in[11];
    const float* temp    = (const float*)d_in[12];
    const float* rq      = (const float*)d_in[13];
    const float* rk      = (const float*)d_in[14];
    const float* rv      = (const float*)d_in[15];
    const float* rg      = (const float*)d_in[16];
    const float* cq      = (const float*)d_in[17];
    const float* ck      = (const float*)d_in[18];
    const float* cv      = (const float*)d_in[19];
    const float* cg      = (const float*)d_in[20];
    const float* fw      = (const float*)d_in[21];
    const float* fb      = (const float*)d_in[22];

    float* ws = (float*)d_ws;
    float* A  = ws;                 // t0 -> x1 (lives to end)
    float* Bf = ws + (size_t)ST;    // g -> out1
    float* Cf = ws + 2*(size_t)ST;  // x1t -> Z2
    float* Df = ws + 3*(size_t)ST;  // out1t -> Z3
    float* Ef = ws + 4*(size_t)ST;  // Z3t
    float* partials = ws + 5*(size_t)ST;   // 576*4096 = 2359296 floats
    float* G1 = partials + 576*4096;       // 16384
    float* M2 = G1 + 16384;                // 16384
    float* Wtr  = M2 + 16384;              // 5 x 4096
    float* Wtc  = Wtr + 4096;
    float* Wf2p = Wtc + 4096;
    float* Wf3p = Wf2p + 4096;
    float* Wfx  = Wf3p + 4096;

    const size_t need = ((size_t)5*ST + 576*4096 + 16384 + 16384 + 5*4096)
                        * sizeof(float);
    if (ws_size < need) {
        fprintf(stderr, "kernel_launch: ws_size %zu < needed %zu\n", ws_size, need);
        return;
    }

    (void)hipFuncSetAttribute((const void*)k_gram_tr,
        hipFuncAttributeMaxDynamicSharedMemorySize, 69632);
    (void)hipFuncSetAttribute((const void*)k_attn_small,
        hipFuncAttributeMaxDynamicSharedMemorySize, 74240);
    (void)hipFuncSetAttribute((const void*)k_attn_fused,
        hipFuncAttributeMaxDynamicSharedMemorySize, 77568);
    (void)hipFuncSetAttribute((const void*)k_attn_row_tr,
        hipFuncAttributeMaxDynamicSharedMemorySize, 77568);
    (void)hipFuncSetAttribute((const void*)k_conv4,
        hipFuncAttributeMaxDynamicSharedMemorySize, 51200);
    (void)hipFuncSetAttribute((const void*)(k_gconv<false,false,false>),
        hipFuncAttributeMaxDynamicSharedMemorySize, 51200);
    (void)hipFuncSetAttribute((const void*)(k_gconv<true,false,false>),
        hipFuncAttributeMaxDynamicSharedMemorySize, 51200);
    (void)hipFuncSetAttribute((const void*)(k_gconv<false,true,false>),
        hipFuncAttributeMaxDynamicSharedMemorySize, 51200);

    const dim3 blk256(256), blk192(192);
    const dim3 gconv(NPIX/128, BB);      // (288, 4)
    const dim3 gline(HH, BB);            // (192, 4)
    const dim3 gtr(6, 6, BB*C);

    // 0) fold weights
    k_small_mats<<<dim3(5), blk256, 0, stream>>>(rq, rk, cq, ck, fw, rv, cv,
                                                 rg, cg, Wtr, Wtc, Wf2p, Wf3p, Wfx);
    // 1) A = pw_w @ x
    k_gconv<false,false,false><<<gconv, blk256, 51200, stream>>>(
        x, nullptr, pw_w, nullptr, nullptr, nullptr, A, 64, 64);
    // 2) B = gelu(dw3x3(A) + dw_b)
    k_dw<<<dim3(HH, BB*C), blk192, 0, stream>>>(A, dw_w, dw_b, Bf);
    // 3) A = x1 = conv2@B + conv0@x + conv2_b + conv0_b
    k_gconv<true,false,false><<<gconv, blk256, 51200, stream>>>(
        Bf, x, conv2_w, conv0_w, conv2_b, conv0_b, A, 64, 64);
    // 4) MERGED gram_part + transpose(A->Cf); transposes backfill gram tail
    k_gram_tr<<<dim3(576 + 9216), blk256, 69632, stream>>>(A, partials, Cf);
    k_gram_reduce<<<dim3(64), blk256, 0, stream>>>(partials, G1);
    k_attn_small<<<dim3(BB), blk256, 74240, stream>>>(G1, attq, attk, attv, attp, temp, M2);
    // 5) B = out1 = M2[b] @ x1
    k_gconv<false,true,false><<<gconv, blk256, 51200, stream>>>(
        A, nullptr, M2, nullptr, nullptr, nullptr, Bf, 64, 64);
    // 6) D = out1t
    k_transpose<<<gtr, blk256, 0, stream>>>(Bf, Df);
    // 7) col attention fused: E = Z3t
    k_attn_fused<<<gline, blk256, 77568, stream>>>(Cf, Wtc, Df, Ef);
    // 8+9) MERGED row attention (C = Z2) + transpose(Ef->Df = Z3);
    //      transposes backfill the attn tail
    k_attn_row_tr<<<dim3(768 + 9216), blk256, 77568, stream>>>(
        A, Wtr, Bf, Cf, Ef, Df);
    // 10) FUSED final conv
    k_conv4<<<gconv, blk256, 51200, stream>>>(
        Bf, Cf, Df, A, fw, Wf2p, Wf3p, Wfx, fb, (float*)d_out);
}

// Round 15
// 767.802 us; speedup vs baseline: 1.0583x; 1.0583x over previous
//
#include <hip/hip_runtime.h>
#include <cstdio>

#define BB 4
#define C 64
#define HH 192
#define WW 192
#define NPIX (HH*WW)            /* 36864 */
#define ST (BB*C*NPIX)          /* 9437184 floats per tensor */

__device__ __forceinline__ float gelu_f(float v) {
    return 0.5f * v * (1.0f + erff(v * 0.70710678118654752440f));
}

// ---- fp16 pair helpers (dot2 path). h2 uses __fp16 to match the native
// return type of __builtin_amdgcn_cvt_pkrtz on gfx950 (R10 compile fix). ----
typedef __fp16 h2 __attribute__((ext_vector_type(2)));

__device__ __forceinline__ h2 pkh2(float lo, float hi) {
#if __has_builtin(__builtin_amdgcn_cvt_pkrtz)
    return __builtin_amdgcn_cvt_pkrtz(lo, hi);
#else
    h2 r; r[0] = (__fp16)lo; r[1] = (__fp16)hi; return r;
#endif
}

__device__ __forceinline__ float dot2f(h2 a, h2 b, float c) {
#if __has_builtin(__builtin_amdgcn_fdot2)
    return __builtin_amdgcn_fdot2(a, b, c, false);
#else
    return c + (float)a[0]*(float)b[0] + (float)a[1]*(float)b[1];
#endif
}

__device__ __forceinline__ void ld4h2(const void* p, h2* d) {
    const float4 f = *reinterpret_cast<const float4*>(p);
    d[0] = __builtin_bit_cast(h2, f.x);
    d[1] = __builtin_bit_cast(h2, f.y);
    d[2] = __builtin_bit_cast(h2, f.z);
    d[3] = __builtin_bit_cast(h2, f.w);
}

// ---------------------------------------------------------------------------
// GEMM-style 1x1 conv (R8-validated). 64(o) x 128(px) tile, 256 thr,
// acc[8][4]/thread. LDS 51200 B -> 3 blocks/CU.
// ---------------------------------------------------------------------------
template<bool TWO_IN, bool PERB, bool DO_GELU>
__global__ __launch_bounds__(256, 3) void k_gconv(
    const float* __restrict__ in1, const float* __restrict__ in2,
    const float* __restrict__ W1, const float* __restrict__ W2,
    const float* __restrict__ bias1, const float* __restrict__ bias2,
    float* __restrict__ out, int ldw1, int ldw2)
{
    extern __shared__ float sm[];
    float* Wl = sm;            // [64][68]  Wl[c][o] = W[o][c]
    float* Xl = sm + 4352;     // [64][132] Xl[c][p]
    const int t = threadIdx.x;
    const int px0 = blockIdx.x * 128;
    const int b = blockIdx.y;
    const size_t base = (size_t)b*(C*NPIX) + px0;
    const int to = t >> 5, tp = t & 31;
    const int o0 = to*8, p0 = tp*4;
    float acc[8][4];
#pragma unroll
    for (int k = 0; k < 8; ++k) {
        float bo = 0.f;
        if (bias1) bo += bias1[o0+k];
        if (bias2) bo += bias2[o0+k];
#pragma unroll
        for (int m = 0; m < 4; ++m) acc[k][m] = bo;
    }
    const int NIN = TWO_IN ? 2 : 1;
#pragma unroll
    for (int inp = 0; inp < NIN; ++inp) {
        const float* In = inp ? in2 : in1;
        const float* Wk = inp ? W2 : (PERB ? W1 + b*4096 : W1);
        const int ldw = inp ? ldw2 : ldw1;
#pragma unroll
        for (int k = 0; k < 16; ++k) {
            const int idx = k*256 + t;
            const int o = idx >> 6, c = idx & 63;
            Wl[c*68 + o] = Wk[o*ldw + c];
        }
#pragma unroll
        for (int k = 0; k < 8; ++k) {
            const int f4 = k*256 + t;
            const int c = f4 >> 5, p4 = (f4 & 31)*4;
            *reinterpret_cast<float4*>(&Xl[c*132 + p4]) =
                *reinterpret_cast<const float4*>(&In[base + (size_t)c*NPIX + p4]);
        }
        __syncthreads();
#pragma unroll 2
        for (int c = 0; c < 64; ++c) {
            const float4 wa = *reinterpret_cast<const float4*>(&Wl[c*68 + o0]);
            const float4 wb = *reinterpret_cast<const float4*>(&Wl[c*68 + o0 + 4]);
            const float4 xv = *reinterpret_cast<const float4*>(&Xl[c*132 + p0]);
            const float wr[8] = {wa.x,wa.y,wa.z,wa.w, wb.x,wb.y,wb.z,wb.w};
            const float xr[4] = {xv.x,xv.y,xv.z,xv.w};
#pragma unroll
            for (int k = 0; k < 8; ++k)
#pragma unroll
                for (int m = 0; m < 4; ++m) acc[k][m] += wr[k]*xr[m];
        }
        __syncthreads();
    }
#pragma unroll
    for (int k = 0; k < 8; ++k) {
        float4 o4;
        if (DO_GELU) {
            o4.x = gelu_f(acc[k][0]); o4.y = gelu_f(acc[k][1]);
            o4.z = gelu_f(acc[k][2]); o4.w = gelu_f(acc[k][3]);
        } else {
            o4.x = acc[k][0]; o4.y = acc[k][1];
            o4.z = acc[k][2]; o4.w = acc[k][3];
        }
        *reinterpret_cast<float4*>(&out[base + (size_t)(o0+k)*NPIX + p0]) = o4;
    }
}

// ---------------------------------------------------------------------------
// FUSED final conv: out = gelu(W1@i1 + W2@i2 + W3@i3 + W4@i4 + bias).
// ---------------------------------------------------------------------------
__global__ __launch_bounds__(256, 3) void k_conv4(
    const float* __restrict__ i1, const float* __restrict__ i2,
    const float* __restrict__ i3, const float* __restrict__ i4,
    const float* __restrict__ W1, const float* __restrict__ W2,
    const float* __restrict__ W3, const float* __restrict__ W4,
    const float* __restrict__ bias, float* __restrict__ out)
{
    extern __shared__ float sm[];
    float* Wl = sm;            // [64][68]
    float* Xl = sm + 4352;     // [64][132]
    const int t = threadIdx.x;
    const int px0 = blockIdx.x * 128;
    const int b = blockIdx.y;
    const size_t base = (size_t)b*(C*NPIX) + px0;
    const int to = t >> 5, tp = t & 31;
    const int o0 = to*8, p0 = tp*4;
    float acc[8][4];
#pragma unroll
    for (int k = 0; k < 8; ++k) {
        const float bo = bias[o0+k];
#pragma unroll
        for (int m = 0; m < 4; ++m) acc[k][m] = bo;
    }
#pragma unroll
    for (int inp = 0; inp < 4; ++inp) {
        const float* In = (inp==0)?i1:(inp==1)?i2:(inp==2)?i3:i4;
        const float* Wk = (inp==0)?W1:(inp==1)?W2:(inp==2)?W3:W4;
        const int ldw = (inp==0)?192:64;
#pragma unroll
        for (int k = 0; k < 16; ++k) {
            const int idx = k*256 + t;
            const int o = idx >> 6, c = idx & 63;
            Wl[c*68 + o] = Wk[o*ldw + c];
        }
#pragma unroll
        for (int k = 0; k < 8; ++k) {
            const int f4 = k*256 + t;
            const int c = f4 >> 5, p4 = (f4 & 31)*4;
            *reinterpret_cast<float4*>(&Xl[c*132 + p4]) =
                *reinterpret_cast<const float4*>(&In[base + (size_t)c*NPIX + p4]);
        }
        __syncthreads();
#pragma unroll 2
        for (int c = 0; c < 64; ++c) {
            const float4 wa = *reinterpret_cast<const float4*>(&Wl[c*68 + o0]);
            const float4 wb = *reinterpret_cast<const float4*>(&Wl[c*68 + o0 + 4]);
            const float4 xv = *reinterpret_cast<const float4*>(&Xl[c*132 + p0]);
            const float wr[8] = {wa.x,wa.y,wa.z,wa.w, wb.x,wb.y,wb.z,wb.w};
            const float xr[4] = {xv.x,xv.y,xv.z,xv.w};
#pragma unroll
            for (int k = 0; k < 8; ++k)
#pragma unroll
                for (int m = 0; m < 4; ++m) acc[k][m] += wr[k]*xr[m];
        }
        __syncthreads();
    }
#pragma unroll
    for (int k = 0; k < 8; ++k) {
        float4 o4;
        o4.x = gelu_f(acc[k][0]); o4.y = gelu_f(acc[k][1]);
        o4.z = gelu_f(acc[k][2]); o4.w = gelu_f(acc[k][3]);
        *reinterpret_cast<float4*>(&out[base + (size_t)(o0+k)*NPIX + p0]) = o4;
    }
}

// ---------------------------------------------------------------------------
// Depthwise 3x3 (pad 1) + bias + GELU, sliding window: 4 outputs/thread down
// a column, 6 rows loaded once (18 loads/4 outputs vs 36 in the 1-output
// version). grid = (H/4, B*C), block = 192 (=W).
// ---------------------------------------------------------------------------
__global__ __launch_bounds__(192) void k_dw(
    const float* __restrict__ t0, const float* __restrict__ w,
    const float* __restrict__ bias, float* __restrict__ g)
{
    const int x = threadIdx.x;
    const int y0 = blockIdx.x * 4;
    const int bc = blockIdx.y;
    const int c = bc & 63;
    const float* img = t0 + (size_t)bc * NPIX;
    const float* wc = w + c * 9;
    const float bias_c = bias[c];
    float L[6], Cm[6], R[6];
#pragma unroll
    for (int r = 0; r < 6; ++r) {
        const int yy = y0 - 1 + r;
        if (yy < 0 || yy > 191) { L[r] = Cm[r] = R[r] = 0.f; continue; }
        const float* row = img + yy*WW;
        Cm[r] = row[x];
        L[r] = (x > 0)   ? row[x-1] : 0.f;
        R[r] = (x < 191) ? row[x+1] : 0.f;
    }
#pragma unroll
    for (int r = 0; r < 4; ++r) {
        float acc = bias_c;
#pragma unroll
        for (int dy = 0; dy < 3; ++dy) {
            acc += L[r+dy]*wc[dy*3+0] + Cm[r+dy]*wc[dy*3+1] + R[r+dy]*wc[dy*3+2];
        }
        g[(size_t)bc*NPIX + (y0+r)*WW + x] = gelu_f(acc);
    }
}

// ---------------------------------------------------------------------------
// Per-batch Gram G1 = X1 * X1^T: partial per 256-pixel chunk.
// ---------------------------------------------------------------------------
__global__ __launch_bounds__(256) void k_gram_part(
    const float* __restrict__ x1p, float* __restrict__ part)
{
    extern __shared__ float lt[];     // [256][68]
    const int chunk = blockIdx.x, b = blockIdx.y, t = threadIdx.x;
    const int gbase = b * (C*NPIX) + chunk * 256;
    for (int idx = t; idx < C*256; idx += 256) {
        const int c = idx >> 8, n = idx & 255;
        lt[n*68 + c] = x1p[gbase + c*NPIX + n];
    }
    __syncthreads();
    const int ti = t & 15, tj = t >> 4;
    float acc[4][4];
#pragma unroll
    for (int r = 0; r < 4; ++r)
#pragma unroll
        for (int s = 0; s < 4; ++s) acc[r][s] = 0.f;
    for (int n = 0; n < 256; ++n) {
        const float4 av = *reinterpret_cast<const float4*>(&lt[n*68 + 4*ti]);
        const float4 bv = *reinterpret_cast<const float4*>(&lt[n*68 + 4*tj]);
        const float ar[4] = {av.x, av.y, av.z, av.w};
        const float br[4] = {bv.x, bv.y, bv.z, bv.w};
#pragma unroll
        for (int r = 0; r < 4; ++r)
#pragma unroll
            for (int s = 0; s < 4; ++s) acc[r][s] += ar[r] * br[s];
    }
    float* pb = part + (b*144 + chunk)*4096;
#pragma unroll
    for (int r = 0; r < 4; ++r)
#pragma unroll
        for (int s = 0; s < 4; ++s) pb[(4*ti+r)*64 + (4*tj+s)] = acc[r][s];
}

__global__ __launch_bounds__(256) void k_gram_reduce(
    const float* __restrict__ part, float* __restrict__ G1)
{
    const int flat = blockIdx.x*256 + threadIdx.x;   // < 16384
    const int b = flat >> 12, ij = flat & 4095;
    float s = 0.f;
    for (int ch = 0; ch < 144; ++ch) s += part[(b*144+ch)*4096 + ij];
    G1[flat] = s;
}

// ---------------------------------------------------------------------------
// Channel-attention collapse: per batch, M2 = Wp * blockdiag(attn) * Wv.
// ---------------------------------------------------------------------------
__global__ __launch_bounds__(256) void k_attn_small(
    const float* __restrict__ G1a, const float* __restrict__ Wq,
    const float* __restrict__ Wk, const float* __restrict__ Wv,
    const float* __restrict__ Wp, const float* __restrict__ temp,
    float* __restrict__ M2)
{
    extern __shared__ float sm[];
    float* g1 = sm;
    float* wa = sm + 4096;
    float* wb = sm + 8192;
    float* u  = sm + 12288;
    float* at = sm + 16384;
    float* nq = sm + 18432;
    float* nk = sm + 18496;
    const int b = blockIdx.x, t = threadIdx.x;
    const float* G = G1a + b*4096;
    for (int i = t; i < 4096; i += 256) { g1[i] = G[i]; wa[i] = Wq[i]; wb[i] = Wk[i]; }
    __syncthreads();
    {
        const int r = t >> 2, q4 = t & 3;
        for (int cc = q4*16; cc < q4*16 + 16; ++cc) {
            float s = 0.f;
            for (int k = 0; k < 64; ++k) s += wa[r*64+k] * g1[k*64+cc];
            u[r*64+cc] = s;
        }
    }
    __syncthreads();
    {
        const int d = t >> 2, kq = t & 3;
        float p = 0.f;
        for (int k = kq*16; k < kq*16 + 16; ++k) {
            float tk = 0.f;
            for (int c2 = 0; c2 < 64; ++c2) tk += g1[k*64+c2] * wb[d*64+c2];
            p += wb[d*64+k] * tk;
        }
        p += __shfl_xor(p, 1);
        p += __shfl_xor(p, 2);
        if (kq == 0) nk[d] = sqrtf(fmaxf(p, 0.f));
    }
    if (t < 64) {
        float s = 0.f;
        for (int c2 = 0; c2 < 64; ++c2) s += u[t*64+c2] * wa[t*64+c2];
        nq[t] = sqrtf(fmaxf(s, 0.f));
    }
    __syncthreads();
    if (t < 64) {
        const int gI = t >> 5;
        const float tg = temp[gI];
        const float dq = fmaxf(nq[t], 1e-12f);
        float row[32];
        float mx = -1e30f;
#pragma unroll
        for (int d2 = 0; d2 < 32; ++d2) {
            const int dd = gI*32 + d2;
            float s = 0.f;
            for (int c2 = 0; c2 < 64; ++c2) s += u[t*64+c2] * wb[dd*64+c2];
            s = s * tg / (dq * fmaxf(nk[dd], 1e-12f));
            row[d2] = s; mx = fmaxf(mx, s);
        }
        float se = 0.f;
#pragma unroll
        for (int d2 = 0; d2 < 32; ++d2) { row[d2] = __expf(row[d2]-mx); se += row[d2]; }
        const float inv = 1.f / se;
#pragma unroll
        for (int d2 = 0; d2 < 32; ++d2) at[t*32+d2] = row[d2]*inv;
    }
    __syncthreads();
    for (int i = t; i < 4096; i += 256) { wa[i] = Wv[i]; wb[i] = Wp[i]; }
    __syncthreads();
    {
        const int m = t >> 2, q4 = t & 3, gI = m >> 5;
        for (int e = q4*16; e < q4*16 + 16; ++e) {
            float s = 0.f;
#pragma unroll
            for (int d2 = 0; d2 < 32; ++d2) s += at[m*32+d2] * wa[(gI*32+d2)*64 + e];
            g1[m*64+e] = s;
        }
    }
    __syncthreads();
    {
        const int o = t >> 2, q4 = t & 3;
        for (int e = q4*16; e < q4*16 + 16; ++e) {
            float s = 0.f;
            for (int m = 0; m < 64; ++m) s += wb[o*64+m] * g1[m*64+e];
            M2[b*4096 + o*64+e] = s;
        }
    }
}

// ---------------------------------------------------------------------------
// Small weight-folding products (unchanged).
// ---------------------------------------------------------------------------
__global__ __launch_bounds__(256) void k_small_mats(
    const float* __restrict__ rq, const float* __restrict__ rk,
    const float* __restrict__ cq, const float* __restrict__ ck,
    const float* __restrict__ fw, const float* __restrict__ rv,
    const float* __restrict__ cv, const float* __restrict__ rg,
    const float* __restrict__ cg,
    float* __restrict__ Wtr, float* __restrict__ Wtc,
    float* __restrict__ Wf2p, float* __restrict__ Wf3p,
    float* __restrict__ Wfx)
{
    const int which = blockIdx.x, t = threadIdx.x;
    const int a = t >> 2, b0 = (t & 3) * 16;
    if (which <= 1) {
        const float* Q = which ? cq : rq;
        const float* Kw = which ? ck : rk;
        float* O = which ? Wtc : Wtr;
        for (int b = b0; b < b0 + 16; ++b) {
            float s = 0.f;
            for (int co = 0; co < 64; ++co) s += Q[co*64 + a] * Kw[co*64 + b];
            O[a*64 + b] = s;
        }
    } else if (which <= 3) {
        const float* Vw = (which == 2) ? rv : cv;
        const float g = (which == 2) ? rg[0] : cg[0];
        const int off = (which == 2) ? 64 : 128;
        float* O = (which == 2) ? Wf2p : Wf3p;
        for (int b = b0; b < b0 + 16; ++b) {
            float s = 0.f;
            for (int m = 0; m < 64; ++m) s += fw[a*192 + off + m] * Vw[m*64 + b];
            O[a*64 + b] = g * s;
        }
    } else {
        for (int b = b0; b < b0 + 16; ++b)
            Wfx[a*64 + b] = fw[a*192 + 64 + b] + fw[a*192 + 128 + b];
    }
}

// ---------------------------------------------------------------------------
// FUSED per-line attention (R13: 132.5us/dispatch). dot2 math, 2 blocks/CU.
// LDS: Xh/Yh h2[32][196] phase A; Ph h2[192][100] overlay phase B;
// lrow fp32[192] persistent @76800B. dyn LDS = 77568 B.
// ---------------------------------------------------------------------------
#define SP 196
#define PSTR 100
__global__ __launch_bounds__(256, 2) void k_attn_fused(
    const float* __restrict__ X, const float* __restrict__ Wt,
    const float* __restrict__ U, float* __restrict__ Z)
{
    extern __shared__ float sm[];
    h2* Xh = reinterpret_cast<h2*>(sm);            // [32][196] pairs along c
    h2* Yh = reinterpret_cast<h2*>(sm + 6272);     // [32][196] pairs along c
    h2* Ph = reinterpret_cast<h2*>(sm);            // [192][100] pairs along j
    float* red  = sm;                              // [192][17] overlay (ph3)
    float* mrow = sm + 3264;                       // 192 (in dead Xh)
    float* lrow = sm + 19200;                      // 192, persistent @76800B
    const int t = threadIdx.x;
    const int h = blockIdx.x, b = blockIdx.y;
    const size_t gbase = (size_t)b*(C*NPIX) + (size_t)h*WW;

    // --- phase 0: load X line (vectorized), pack fp16 pairs along c ---
#pragma unroll
    for (int k = 0; k < 6; ++k) {
        const int idx = k*256 + t;                 // < 32*48
        const int cc = idx / 48, jg = (idx - cc*48) * 4;
        const float4 lo = *reinterpret_cast<const float4*>(
            &X[gbase + (size_t)(2*cc)*NPIX + jg]);
        const float4 hi = *reinterpret_cast<const float4*>(
            &X[gbase + (size_t)(2*cc+1)*NPIX + jg]);
        float4 o;
        o.x = __builtin_bit_cast(float, pkh2(lo.x, hi.x));
        o.y = __builtin_bit_cast(float, pkh2(lo.y, hi.y));
        o.z = __builtin_bit_cast(float, pkh2(lo.z, hi.z));
        o.w = __builtin_bit_cast(float, pkh2(lo.w, hi.w));
        *reinterpret_cast<float4*>(&Xh[cc*SP + jg]) = o;
    }
    __syncthreads();

    // --- phase 1: Y = sum_a Wt[a][c] X[a][j], dot2 pairs along a ---
    {
        const int tc = t & 15, tjy = t >> 4;
        const int c0 = 4*tc, j0y = 12*tjy;
        float accy[4][12];
#pragma unroll
        for (int k = 0; k < 4; ++k)
#pragma unroll
            for (int m = 0; m < 12; ++m) accy[k][m] = 0.f;
        for (int aa = 0; aa < 32; ++aa) {
            const float4 wlo = *reinterpret_cast<const float4*>(&Wt[(2*aa)*64 + c0]);
            const float4 whi = *reinterpret_cast<const float4*>(&Wt[(2*aa+1)*64 + c0]);
            h2 wh[4];
            wh[0] = pkh2(wlo.x, whi.x); wh[1] = pkh2(wlo.y, whi.y);
            wh[2] = pkh2(wlo.z, whi.z); wh[3] = pkh2(wlo.w, whi.w);
            h2 xh[12];
            ld4h2(&Xh[aa*SP + j0y],     xh);
            ld4h2(&Xh[aa*SP + j0y + 4], xh+4);
            ld4h2(&Xh[aa*SP + j0y + 8], xh+8);
#pragma unroll
            for (int k = 0; k < 4; ++k)
#pragma unroll
                for (int m = 0; m < 12; ++m)
                    accy[k][m] = dot2f(wh[k], xh[m], accy[k][m]);
        }
#pragma unroll
        for (int m = 0; m < 12; ++m) {
            Yh[(2*tc)*SP + j0y + m]   = pkh2(accy[0][m], accy[1][m]);
            Yh[(2*tc+1)*SP + j0y + m] = pkh2(accy[2][m], accy[3][m]);
        }
    }
    __syncthreads();

    // --- phase 2: S = X^T Y, dot2 pairs along c, fp32 12x12 acc ---
    const int ti = t & 15, tj = t >> 4;
    const int i0 = ti*12, j0 = tj*12;
    float acc[12][12];
#pragma unroll
    for (int r = 0; r < 12; ++r)
#pragma unroll
        for (int s = 0; s < 12; ++s) acc[r][s] = 0.f;
#pragma unroll 2
    for (int cc = 0; cc < 32; ++cc) {
        h2 xh[12], yh[12];
        ld4h2(&Xh[cc*SP + i0],     xh);
        ld4h2(&Xh[cc*SP + i0 + 4], xh+4);
        ld4h2(&Xh[cc*SP + i0 + 8], xh+8);
        ld4h2(&Yh[cc*SP + j0],     yh);
        ld4h2(&Yh[cc*SP + j0 + 4], yh+4);
        ld4h2(&Yh[cc*SP + j0 + 8], yh+8);
#pragma unroll
        for (int r = 0; r < 12; ++r)
#pragma unroll
            for (int s = 0; s < 12; ++s)
                acc[r][s] = dot2f(xh[r], yh[s], acc[r][s]);
    }
    __syncthreads();   // Xh/Yh dead; red overlays Xh

    // --- phase 3: softmax over rows (fp32; P~ left unnormalized) ---
#pragma unroll
    for (int r = 0; r < 12; ++r) {
        float pm = acc[r][0];
#pragma unroll
        for (int s = 1; s < 12; ++s) pm = fmaxf(pm, acc[r][s]);
        red[(i0 + r)*17 + tj] = pm;
    }
    __syncthreads();
    if (t < 192) {
        float m = red[t*17];
#pragma unroll
        for (int k = 1; k < 16; ++k) m = fmaxf(m, red[t*17 + k]);
        mrow[t] = m;
    }
    __syncthreads();
#pragma unroll
    for (int r = 0; r < 12; ++r) {
        const float mi = mrow[i0 + r];
        float ps = 0.f;
#pragma unroll
        for (int s = 0; s < 12; ++s) {
            acc[r][s] = __expf(acc[r][s] - mi);
            ps += acc[r][s];
        }
        red[(i0 + r)*17 + tj] = ps;
    }
    __syncthreads();
    if (t < 192) {
        float l = 0.f;
#pragma unroll
        for (int k = 0; k < 16; ++k) l += red[t*17 + k];
        lrow[t] = 1.f / l;
    }
    __syncthreads();

    // --- phase 4: store unnormalized P~ fp16, pairs along j ---
    {
        const int jh0 = j0 >> 1;       // 6*tj
#pragma unroll
        for (int r = 0; r < 12; ++r)
#pragma unroll
            for (int q = 0; q < 6; ++q)
                Ph[(i0 + r)*PSTR + jh0 + q] = pkh2(acc[r][2*q], acc[r][2*q+1]);
    }
    __syncthreads();

    // --- phase 5: Z = lrow * (U @ P~^T); U cvt'd on fly, dot2 along j ---
    const int ci = t & 15, ii = t >> 4;
    const int c0z = 4*ci, i0z = 12*ii;
    const float* Ub = U + gbase;
    float accz[4][12];
#pragma unroll
    for (int k = 0; k < 4; ++k)
#pragma unroll
        for (int m = 0; m < 12; ++m) accz[k][m] = 0.f;
    for (int jt = 0; jt < 192; jt += 8) {
        h2 uh[4][4];
#pragma unroll
        for (int k = 0; k < 4; ++k) {
            const float4 ua = *reinterpret_cast<const float4*>(&Ub[(size_t)(c0z+k)*NPIX + jt]);
            const float4 ub = *reinterpret_cast<const float4*>(&Ub[(size_t)(c0z+k)*NPIX + jt + 4]);
            uh[k][0] = pkh2(ua.x, ua.y); uh[k][1] = pkh2(ua.z, ua.w);
            uh[k][2] = pkh2(ub.x, ub.y); uh[k][3] = pkh2(ub.z, ub.w);
        }
        h2 ph[12][4];
#pragma unroll
        for (int m = 0; m < 12; ++m)
            ld4h2(&Ph[(i0z+m)*PSTR + (jt >> 1)], ph[m]);
#pragma unroll
        for (int k = 0; k < 4; ++k)
#pragma unroll
            for (int m = 0; m < 12; ++m) {
                float a = accz[k][m];
                a = dot2f(uh[k][0], ph[m][0], a);
                a = dot2f(uh[k][1], ph[m][1], a);
                a = dot2f(uh[k][2], ph[m][2], a);
                a = dot2f(uh[k][3], ph[m][3], a);
                accz[k][m] = a;
            }
    }
    float lr[12];
#pragma unroll
    for (int m = 0; m < 12; ++m) lr[m] = lrow[i0z + m];
#pragma unroll
    for (int k = 0; k < 4; ++k) {
        float* zr = Z + gbase + (size_t)(c0z + k)*NPIX + i0z;
        float4 o0, o1, o2;
        o0.x = accz[k][0]*lr[0]; o0.y = accz[k][1]*lr[1];  o0.z = accz[k][2]*lr[2];   o0.w = accz[k][3]*lr[3];
        o1.x = accz[k][4]*lr[4]; o1.y = accz[k][5]*lr[5];  o1.z = accz[k][6]*lr[6];   o1.w = accz[k][7]*lr[7];
        o2.x = accz[k][8]*lr[8]; o2.y = accz[k][9]*lr[9];  o2.z = accz[k][10]*lr[10]; o2.w = accz[k][11]*lr[11];
        *reinterpret_cast<float4*>(zr)     = o0;
        *reinterpret_cast<float4*>(zr + 4) = o1;
        *reinterpret_cast<float4*>(zr + 8) = o2;
    }
}

// ---------------------------------------------------------------------------
// HW transpose per image: out[img][x][y] = in[img][y][x]. grid (6,6,B*C).
// ---------------------------------------------------------------------------
__global__ __launch_bounds__(256) void k_transpose(
    const float* __restrict__ in, float* __restrict__ out)
{
    __shared__ float tile[32][33];
    const int tx = threadIdx.x & 31, ty = threadIdx.x >> 5;
    const int x0 = blockIdx.x*32, y0 = blockIdx.y*32;
    const float* img = in + blockIdx.z * NPIX;
    float* og = out + blockIdx.z * NPIX;
#pragma unroll
    for (int r = ty; r < 32; r += 8) tile[r][tx] = img[(y0+r)*WW + x0+tx];
    __syncthreads();
#pragma unroll
    for (int r = ty; r < 32; r += 8) og[(x0+r)*WW + (y0+tx)] = tile[tx][r];
}

// ---------------------------------------------------------------------------
// Dual transpose: z < B*C -> inA->outA, else inB->outB (one launch ramp).
// ---------------------------------------------------------------------------
__global__ __launch_bounds__(256) void k_transpose2(
    const float* __restrict__ inA, float* __restrict__ outA,
    const float* __restrict__ inB, float* __restrict__ outB)
{
    __shared__ float tile[32][33];
    const int tx = threadIdx.x & 31, ty = threadIdx.x >> 5;
    const int x0 = blockIdx.x*32, y0 = blockIdx.y*32;
    const int z = blockIdx.z;
    const float* img = (z < BB*C) ? inA + (size_t)z*NPIX
                                  : inB + (size_t)(z - BB*C)*NPIX;
    float* og = (z < BB*C) ? outA + (size_t)z*NPIX
                           : outB + (size_t)(z - BB*C)*NPIX;
#pragma unroll
    for (int r = ty; r < 32; r += 8) tile[r][tx] = img[(y0+r)*WW + x0+tx];
    __syncthreads();
#pragma unroll
    for (int r = ty; r < 32; r += 8) og[(x0+r)*WW + (y0+tx)] = tile[tx][r];
}

// ---------------------------------------------------------------------------
extern "C" void kernel_launch(void* const* d_in, const int* in_sizes, int n_in,
                              void* d_out, int out_size, void* d_ws, size_t ws_size,
                              hipStream_t stream) {
    const float* x       = (const float*)d_in[0];
    const float* pw_w    = (const float*)d_in[1];
    const float* dw_w    = (const float*)d_in[2];
    const float* dw_b    = (const float*)d_in[3];
    const float* conv2_w = (const float*)d_in[4];
    const float* conv2_b = (const float*)d_in[5];
    const float* conv0_w = (const float*)d_in[6];
    const float* conv0_b = (const float*)d_in[7];
    const float* attq    = (const float*)d_in[8];
    const float* attk    = (const float*)d_in[9];
    const float* attv    = (const float*)d_in[10];
    const float* attp    = (const float*)d_in[11];
    const float* temp    = (const float*)d_in[12];
    const float* rq      = (const float*)d_in[13];
    const float* rk      = (const float*)d_in[14];
    const float* rv      = (const float*)d_in[15];
    const float* rg      = (const float*)d_in[16];
    const float* cq      = (const float*)d_in[17];
    const float* ck      = (const float*)d_in[18];
    const float* cv      = (const float*)d_in[19];
    const float* cg      = (const float*)d_in[20];
    const float* fw      = (const float*)d_in[21];
    const float* fb      = (const float*)d_in[22];

    float* ws = (float*)d_ws;
    float* A  = ws;                 // t0 -> x1 (lives to end)
    float* Bf = ws + (size_t)ST;    // g -> out1
    float* Cf = ws + 2*(size_t)ST;  // x1t -> Z2
    float* Df = ws + 3*(size_t)ST;  // out1t -> Z3
    float* Ef = ws + 4*(size_t)ST;  // Z3t
    float* partials = ws + 5*(size_t)ST;   // 576*4096 = 2359296 floats
    float* G1 = partials + 576*4096;       // 16384
    float* M2 = G1 + 16384;                // 16384
    float* Wtr  = M2 + 16384;              // 5 x 4096
    float* Wtc  = Wtr + 4096;
    float* Wf2p = Wtc + 4096;
    float* Wf3p = Wf2p + 4096;
    float* Wfx  = Wf3p + 4096;

    const size_t need = ((size_t)5*ST + 576*4096 + 16384 + 16384 + 5*4096)
                        * sizeof(float);
    if (ws_size < need) {
        fprintf(stderr, "kernel_launch: ws_size %zu < needed %zu\n", ws_size, need);
        return;
    }

    (void)hipFuncSetAttribute((const void*)k_gram_part,
        hipFuncAttributeMaxDynamicSharedMemorySize, 69632);
    (void)hipFuncSetAttribute((const void*)k_attn_small,
        hipFuncAttributeMaxDynamicSharedMemorySize, 74240);
    (void)hipFuncSetAttribute((const void*)k_attn_fused,
        hipFuncAttributeMaxDynamicSharedMemorySize, 77568);
    (void)hipFuncSetAttribute((const void*)k_conv4,
        hipFuncAttributeMaxDynamicSharedMemorySize, 51200);
    (void)hipFuncSetAttribute((const void*)(k_gconv<false,false,false>),
        hipFuncAttributeMaxDynamicSharedMemorySize, 51200);
    (void)hipFuncSetAttribute((const void*)(k_gconv<true,false,false>),
        hipFuncAttributeMaxDynamicSharedMemorySize, 51200);
    (void)hipFuncSetAttribute((const void*)(k_gconv<false,true,false>),
        hipFuncAttributeMaxDynamicSharedMemorySize, 51200);

    const dim3 blk256(256), blk192(192);
    const dim3 gconv(NPIX/128, BB);      // (288, 4)
    const dim3 ggram(NPIX/256, BB);      // (144, 4)
    const dim3 gline(HH, BB);            // (192, 4)
    const dim3 gtr(6, 6, BB*C);
    const dim3 gtr2(6, 6, 2*BB*C);
    const dim3 gdw(HH/4, BB*C);          // (48, 256)

    // 0) fold weights
    k_small_mats<<<dim3(5), blk256, 0, stream>>>(rq, rk, cq, ck, fw, rv, cv,
                                                 rg, cg, Wtr, Wtc, Wf2p, Wf3p, Wfx);
    // 1) A = pw_w @ x
    k_gconv<false,false,false><<<gconv, blk256, 51200, stream>>>(
        x, nullptr, pw_w, nullptr, nullptr, nullptr, A, 64, 64);
    // 2) B = gelu(dw3x3(A) + dw_b)  (sliding-window, 4 rows/thread)
    k_dw<<<gdw, blk192, 0, stream>>>(A, dw_w, dw_b, Bf);
    // 3) A = x1 = conv2@B + conv0@x + conv2_b + conv0_b
    k_gconv<true,false,false><<<gconv, blk256, 51200, stream>>>(
        Bf, x, conv2_w, conv0_w, conv2_b, conv0_b, A, 64, 64);
    // 4) channel attention collapse -> M2
    k_gram_part<<<ggram, blk256, 69632, stream>>>(A, partials);
    k_gram_reduce<<<dim3(64), blk256, 0, stream>>>(partials, G1);
    k_attn_small<<<dim3(BB), blk256, 74240, stream>>>(G1, attq, attk, attv, attp, temp, M2);
    // 5) B = out1 = M2[b] @ x1
    k_gconv<false,true,false><<<gconv, blk256, 51200, stream>>>(
        A, nullptr, M2, nullptr, nullptr, nullptr, Bf, 64, 64);
    // 6) C = x1t, D = out1t (one dual-transpose launch)
    k_transpose2<<<gtr2, blk256, 0, stream>>>(A, Cf, Bf, Df);
    // 7) col attention fused: E = Z3t
    k_attn_fused<<<gline, blk256, 77568, stream>>>(Cf, Wtc, Df, Ef);
    // 8) D = Z3 = transpose(Z3t)
    k_transpose<<<gtr, blk256, 0, stream>>>(Ef, Df);
    // 9) row attention fused: C = Z2
    k_attn_fused<<<gline, blk256, 77568, stream>>>(A, Wtr, Bf, Cf);
    // 10) FUSED final conv
    k_conv4<<<gconv, blk256, 51200, stream>>>(
        Bf, Cf, Df, A, fw, Wf2p, Wf3p, Wfx, fb, (float*)d_out);
}